// Round 11
// baseline (112.807 us; speedup 1.0000x reference)
//
#include <hip/hip_runtime.h>
#include <hip/hip_bf16.h>

typedef __bf16 bf16x8 __attribute__((ext_vector_type(8)));
typedef float f32x16 __attribute__((ext_vector_type(16)));
typedef unsigned int u32;
typedef unsigned short u16;

// ws layout (bytes):
//   [0,       524288)  WtP   : bf16 W_enc pack [u=32][ks16=16-unit][lane=64][e=8]
//   [524288,  655360)  bias2p: f32 [64][512]
//   [655360,  917504)  logits: f32 [65536]
#define WS_WT     0
#define WS_BIAS   524288
#define WS_LOGITS 655360

__device__ __forceinline__ u16 f2bf(float f) {
    __bf16 h = (__bf16)f;
    return __builtin_bit_cast(u16, h);
}

__device__ __forceinline__ void gload_lds16(const void* g, void* l) {
    __builtin_amdgcn_global_load_lds(
        (const __attribute__((address_space(1))) u32*)g,
        (__attribute__((address_space(3))) u32*)l, 16, 0, 0);
}

__device__ __forceinline__ bf16x8 cvt8(float4 a, float4 b) {
    bf16x8 r;
    r[0] = (__bf16)a.x; r[1] = (__bf16)a.y; r[2] = (__bf16)a.z; r[3] = (__bf16)a.w;
    r[4] = (__bf16)b.x; r[5] = (__bf16)b.y; r[6] = (__bf16)b.z; r[7] = (__bf16)b.w;
    return r;
}

// K0a: pack W_enc. unit u16B: l=u&63, ks=(u>>6)&31, p=u>>11.
// elem e: W[k][n], n = p*32 + (l&31), k = ks*16 + (l>>5)*8 + e
__global__ void k_wt(const float* __restrict__ W, u16* __restrict__ WtP) {
    int u = blockIdx.x * 256 + threadIdx.x;     // 32768 units
    int l = u & 63, ks = (u >> 6) & 31, p = u >> 11;
    int n = p * 32 + (l & 31);
    int k0 = ks * 16 + (l >> 5) * 8;
    u16 o[8];
    #pragma unroll
    for (int e = 0; e < 8; ++e)
        o[e] = f2bf(W[(k0 + e) * 512 + n]);
    *(uint4*)(WtP + (size_t)u * 8) = *(const uint4*)o;
}

// K0b: bias2p = dec·W_dec + b_dec + b_enc; blocks 0..63 also zero out[0..32768)
__global__ void k_bias2(const float* __restrict__ dec, const float* __restrict__ Wd,
                        const float* __restrict__ b_dec, const float* __restrict__ b_enc,
                        float* __restrict__ bias2p, float* __restrict__ out0) {
    int blk = blockIdx.x;
    int b = blk >> 2, nc = blk & 3;
    int t = threadIdx.x;
    if (blk < 64) {
        out0[blk * 512 + t * 2] = 0.f;
        out0[blk * 512 + t * 2 + 1] = 0.f;
    }
    __shared__ float sdec[512];
    __shared__ float red[256];
    for (int k = t; k < 512; k += 256) sdec[k] = dec[b * 512 + k];
    __syncthreads();
    int n = nc * 128 + (t & 127);
    int kh = t >> 7;
    float acc = 0.f;
    int k0 = kh * 256;
    #pragma unroll 4
    for (int k = k0; k < k0 + 256; ++k)
        acc += sdec[k] * Wd[k * 512 + n];
    red[t] = acc;
    __syncthreads();
    if (t < 128) {
        int nn = nc * 128 + t;
        bias2p[b * 512 + nn] = red[t] + red[t + 128] + b_dec[nn] + b_enc[nn];
    }
}

// K1: fused enc@W_enc + bias -> relu -> ·Wf  =>  logits [B*L]
// 512 blocks x 256 thr (4 waves), 2 blocks/CU (68KB LDS). Block = 128 rows.
// Counted-vmcnt schedule: VMEM queue NEVER drains to 0 until the tail.
// Prologue: A dbuf rounds, vmcnt(8). Main: 4-deep B ring, vmcnt(8)/(4)/(0).
__global__ __launch_bounds__(256, 2) void k_logits(
        const float* __restrict__ enc, const u16* __restrict__ WtP,
        const float* __restrict__ bias2p, const float* __restrict__ Wf,
        float* __restrict__ logits) {
    // [0,65536) = 4x16KB B-ring (prologue: X0=[0,32K), X1=[32K,64K))
    // [65536,67584) bias row, [67584,69632) Wf
    __shared__ __align__(16) char lds[69632];

    int t = threadIdx.x;
    int lane = t & 63;
    int w = t >> 6;                 // wave 0..3
    int blk = blockIdx.x;           // 512 blocks of 128 rows
    int b = blk >> 3;               // batch
    int cl = lane & 31;
    int hi = lane >> 5;
    int rloc = lane & 15;
    int parity = (lane >> 4) & 1;
    int myswz = rloc & 7;

    // A tile s (16 rows fp32, 32KB) -> lds[X_], source col-XOR-swizzled
    #define STAGEA(s_, X_)                                                        \
        {                                                                         \
            size_t base_ = ((size_t)blk * 128 + (s_) * 16) * 2048;                \
            _Pragma("unroll")                                                     \
            for (int j = 0; j < 8; ++j) {                                         \
                int u_ = t + j * 256;                                             \
                int r_ = u_ >> 7, c_ = u_ & 127;                                  \
                const char* src_ = (const char*)enc + base_ + (size_t)r_ * 2048   \
                                   + ((size_t)(c_ ^ (r_ & 7)) * 16);              \
                gload_lds16(src_, lds + (X_) + (size_t)u_ * 16);                  \
            }                                                                     \
        }
    // B unit u (16KB = 16 frag-rows) -> lds[off_]
    #define STAGEB(u_, off_)                                                      \
        {                                                                         \
            const char* s_ = (const char*)WtP + (size_t)(u_) * 16384 + t * 16;    \
            _Pragma("unroll")                                                     \
            for (int j = 0; j < 4; ++j)                                           \
                gload_lds16(s_ + j * 4096, lds + (off_) + t * 16 + j * 4096);     \
        }
    #define REDIST(X_)                                                            \
        {                                                                         \
            _Pragma("unroll")                                                     \
            for (int f = 0; f < 32; ++f) {                                        \
                int c0 = (f * 4 + hi * 2) ^ myswz;                                \
                int c1 = (f * 4 + hi * 2 + 1) ^ myswz;                            \
                float4 lo = *(const float4*)(lds + (X_) + rloc * 2048 + c0 * 16); \
                float4 h4 = *(const float4*)(lds + (X_) + rloc * 2048 + c1 * 16); \
                A[f] = cvt8(lo, h4);                                              \
            }                                                                     \
        }

    // ---- prologue ----
    STAGEA(0, 0)
    STAGEA(1, 32768)
    if (w == 0) {                   // bias row -> lds[65536..)
        #pragma unroll
        for (int j = 0; j < 2; ++j)
            gload_lds16((const char*)(bias2p + b * 512 + j * 256) + lane * 16,
                        lds + 65536 + j * 1024 + lane * 16);
    } else if (w == 1) {            // Wf -> lds[67584..)
        #pragma unroll
        for (int j = 0; j < 2; ++j)
            gload_lds16((const char*)(Wf + j * 256) + lane * 16,
                        lds + 67584 + j * 1024 + lane * 16);
    }

    bf16x8 A[32];
    for (int s = 0; s < 7; ++s) {
        asm volatile("s_waitcnt vmcnt(8)" ::: "memory");   // A(s) landed; A(s+1) in flight
        __builtin_amdgcn_s_barrier();
        if ((s >> 1) == w && (s & 1) == parity) REDIST((s & 1) * 32768)
        asm volatile("s_waitcnt lgkmcnt(0)" ::: "memory");
        __builtin_amdgcn_s_barrier();
        if (s < 6) STAGEA(s + 2, (s & 1) * 32768)
    }
    asm volatile("s_waitcnt vmcnt(0)" ::: "memory");       // round 7 + bias/Wf drain
    __builtin_amdgcn_s_barrier();
    if (w == 3 && parity == 1) REDIST(32768)
    asm volatile("s_waitcnt lgkmcnt(0)" ::: "memory");
    __builtin_amdgcn_s_barrier();
    #pragma unroll
    for (int f = 0; f < 32; ++f)
        asm volatile("" : "+v"(A[f]));                      // pin A resident

    // prime B ring: units 0,1,2 (12 loads/wave in flight)
    STAGEB(0, 0)
    STAGEB(1, 16384)
    STAGEB(2, 32768)

    float pr[16];
    #pragma unroll
    for (int r = 0; r < 16; ++r) pr[r] = 0.f;

    #define CONSUME(accv, Abase, off_)                                            \
        {                                                                         \
            __builtin_amdgcn_s_setprio(1);                                        \
            _Pragma("unroll")                                                     \
            for (int i = 0; i < 16; ++i) {                                        \
                uint4 braw = *(const uint4*)(lds + (off_) + i * 1024 + lane * 16);\
                accv = __builtin_amdgcn_mfma_f32_32x32x16_bf16(                   \
                    A[(Abase) + i], __builtin_bit_cast(bf16x8, braw), accv, 0, 0, 0); \
            }                                                                     \
            __builtin_amdgcn_s_setprio(0);                                        \
        }
    #define EPILOG(p_)                                                            \
        {                                                                         \
            float bias = *(const float*)(lds + 65536 + ((p_) * 32 + cl) * 4);     \
            float wfv  = *(const float*)(lds + 67584 + ((p_) * 32 + cl) * 4);     \
            _Pragma("unroll")                                                     \
            for (int r = 0; r < 16; ++r) {                                        \
                float v = acc0[r] + acc1[r] + bias;                               \
                v = v > 0.f ? v : 0.f;                                            \
                pr[r] += v * wfv;                                                 \
            }                                                                     \
        }

    for (int p = 0; p < 15; ++p) {
        int q = (p & 1) << 1;                 // ring idx of unit 2p
        int bufA = q * 16384;
        int bufB = (q | 1) * 16384;
        int stA = ((q ^ 2) | 1) * 16384;      // ring[(2p+3)&3]
        int stB = (q ^ 2) * 16384;            // ring[(2p+4)&3] -- wait: (2p+4)&3 == q
        stB = q * 16384;                      // corrected: unit 2p+4 lands where 2p was
        // half 0 (unit 2p)
        asm volatile("s_waitcnt vmcnt(8)" ::: "memory");
        __builtin_amdgcn_s_barrier();
        STAGEB(2 * p + 3, stA)
        f32x16 acc0 = {};
        CONSUME(acc0, 0, bufA)
        // half 1 (unit 2p+1)
        asm volatile("s_waitcnt vmcnt(8)" ::: "memory");
        __builtin_amdgcn_s_barrier();
        if (p < 14) STAGEB(2 * p + 4, stB)
        f32x16 acc1 = {};
        CONSUME(acc1, 16, bufB)
        EPILOG(p)
    }
    {   // p = 15 peeled (units 30,31 in ring[2],ring[3])
        asm volatile("s_waitcnt vmcnt(4)" ::: "memory");
        __builtin_amdgcn_s_barrier();
        f32x16 acc0 = {};
        CONSUME(acc0, 0, 32768)
        asm volatile("s_waitcnt vmcnt(0)" ::: "memory");
        __builtin_amdgcn_s_barrier();
        f32x16 acc1 = {};
        CONSUME(acc1, 16, 49152)
        EPILOG(15)
    }

    // reduce over the 32 col-lanes; lane cl==0 writes 32 rows
    #pragma unroll
    for (int r = 0; r < 16; ++r) {
        float v = pr[r];
        v += __shfl_xor(v, 1, 64);
        v += __shfl_xor(v, 2, 64);
        v += __shfl_xor(v, 4, 64);
        v += __shfl_xor(v, 8, 64);
        v += __shfl_xor(v, 16, 64);
        if (cl == 0)
            logits[blk * 128 + w * 32 + (r & 3) + 8 * (r >> 2) + 4 * hi] = v;
    }
}

// K2: softmax over L per batch (b_full omitted: softmax is shift-invariant)
__global__ void k_softmax(const float* __restrict__ logits, float* __restrict__ alpha) {
    int b = blockIdx.x;
    int t = threadIdx.x;
    __shared__ float red[256];
    float4 v = ((const float4*)(logits + b * 1024))[t];
    float mx = fmaxf(fmaxf(v.x, v.y), fmaxf(v.z, v.w));
    red[t] = mx;
    __syncthreads();
    for (int s = 128; s > 0; s >>= 1) {
        if (t < s) red[t] = fmaxf(red[t], red[t + s]);
        __syncthreads();
    }
    mx = red[0];
    __syncthreads();
    float4 e;
    e.x = expf(v.x - mx); e.y = expf(v.y - mx);
    e.z = expf(v.z - mx); e.w = expf(v.w - mx);
    red[t] = e.x + e.y + e.z + e.w;
    __syncthreads();
    for (int s = 128; s > 0; s >>= 1) {
        if (t < s) red[t] += red[t + s];
        __syncthreads();
    }
    float inv = 1.0f / red[0];
    float4 o;
    o.x = e.x * inv; o.y = e.y * inv; o.z = e.z * inv; o.w = e.w * inv;
    ((float4*)(alpha + b * 1024))[t] = o;
}

// K3: weighted sums over l-chunks of 128, atomicAdd into out (zeroed by k_bias2)
__global__ void k_wsum_part(const float* __restrict__ enc, const float* __restrict__ alpha,
                            float* __restrict__ out) {
    int blk = blockIdx.x;           // 512 blocks: b = blk>>3, chunk c = blk&7
    int b = blk >> 3, c = blk & 7;
    int t = threadIdx.x;
    int col = (t & 127) * 4;
    int lh = t >> 7;
    const float* ep = enc + (size_t)(b * 1024 + c * 128) * 512;
    const float* al = alpha + b * 1024 + c * 128;
    float4 s = {0.f, 0.f, 0.f, 0.f};
    #pragma unroll 4
    for (int i = 0; i < 64; ++i) {
        int l = i * 2 + lh;
        float a = al[l];
        float4 e = *(const float4*)(ep + (size_t)l * 512 + col);
        s.x += e.x * a; s.y += e.y * a; s.z += e.z * a; s.w += e.w * a;
    }
    __shared__ float red[2][512];
    *(float4*)&red[lh][col] = s;
    __syncthreads();
    if (t < 128) {
        float4 a0 = *(const float4*)&red[0][t * 4];
        float4 a1 = *(const float4*)&red[1][t * 4];
        float* op = out + b * 512 + t * 4;
        atomicAdd(op + 0, a0.x + a1.x);
        atomicAdd(op + 1, a0.y + a1.y);
        atomicAdd(op + 2, a0.z + a1.z);
        atomicAdd(op + 3, a0.w + a1.w);
    }
}

extern "C" void kernel_launch(void* const* d_in, const int* in_sizes, int n_in,
                              void* d_out, int out_size, void* d_ws, size_t ws_size,
                              hipStream_t stream) {
    const float* enc    = (const float*)d_in[0];  // [64,1024,512]
    const float* dec    = (const float*)d_in[1];  // [64,512]
    const float* W_enc  = (const float*)d_in[2];  // [512,512]
    const float* b_enc  = (const float*)d_in[3];  // [512]
    const float* W_dec  = (const float*)d_in[4];  // [512,512]
    const float* b_dec  = (const float*)d_in[5];  // [512]
    const float* W_full = (const float*)d_in[6];  // [512]
    // d_in[7] = b_full: unused (softmax is shift-invariant)

    float* out = (float*)d_out;                   // [0,32768) weighted enc; [32768,98304) alpha
    char* ws = (char*)d_ws;
    u16* WtP      = (u16*)(ws + WS_WT);
    float* bias2p = (float*)(ws + WS_BIAS);
    float* logits = (float*)(ws + WS_LOGITS);
    float* alpha  = out + 32768;

    hipLaunchKernelGGL(k_wt,        dim3(128), dim3(256), 0, stream, W_enc, WtP);
    hipLaunchKernelGGL(k_bias2,     dim3(256), dim3(256), 0, stream,
                       dec, W_dec, b_dec, b_enc, bias2p, out);
    hipLaunchKernelGGL(k_logits,    dim3(512), dim3(256), 0, stream,
                       enc, WtP, bias2p, W_full, logits);
    hipLaunchKernelGGL(k_softmax,   dim3(64),  dim3(256), 0, stream, logits, alpha);
    hipLaunchKernelGGL(k_wsum_part, dim3(512), dim3(256), 0, stream, enc, alpha, out);
}